// Round 11
// baseline (1496.722 us; speedup 1.0000x reference)
//
#include <hip/hip_runtime.h>
#include <hip/hip_bf16.h>

#define B_   16
#define T_   2048
#define E_   1024
#define S_   2000
#define HID_ 150
#define GI_  3072

typedef __attribute__((ext_vector_type(8))) short short8;   // 8 bf16 (4 VGPRs)
typedef __attribute__((ext_vector_type(4))) float f32x4;

constexpr int NPAD  = 160;   // HID padded to 10 MFMA col-tiles
constexpr int LSTR  = 168;   // hl row stride (bf16): 336 B
constexpr int MROWS = 64;    // rows per MLP block

__device__ __forceinline__ void gload16(const void* gsrc, void* ldst) {
    __builtin_amdgcn_global_load_lds(
        (const __attribute__((address_space(1))) unsigned int*)gsrc,
        (__attribute__((address_space(3))) unsigned int*)ldst,
        16, 0, 0);   // 16B/lane, wave-uniform LDS base + lane*16
}

__device__ __forceinline__ short8 pack8(float4 a, float4 b) {
    union { __hip_bfloat162 h[4]; short8 s; } u;
    u.h[0] = __float22bfloat162_rn(make_float2(a.x, a.y));
    u.h[1] = __float22bfloat162_rn(make_float2(a.z, a.w));
    u.h[2] = __float22bfloat162_rn(make_float2(b.x, b.y));
    u.h[3] = __float22bfloat162_rn(make_float2(b.z, b.w));
    return u.s;
}

// All four weight transposes (f32 [K][150] -> bf16 [160][K], zero-padded).
__global__ __launch_bounds__(256)
void transpose_all(const float* __restrict__ Wa1, const float* __restrict__ Wa2,
                   const float* __restrict__ Ws1, const float* __restrict__ Ws2,
                   __hip_bfloat16* __restrict__ Wt1a, __hip_bfloat16* __restrict__ Wt2a,
                   __hip_bfloat16* __restrict__ Wt1s, __hip_bfloat16* __restrict__ Wt2s)
{
    const int s0 = 160 * 1024, s1 = 160 * 160, s2 = 160 * 3072, s3 = 160 * 160;
    int i = blockIdx.x * 256 + threadIdx.x;
    if (i < s0) {
        int n = i >> 10, k = i & 1023;
        Wt1a[i] = __float2bfloat16(n < HID_ ? Wa1[k * HID_ + n] : 0.f);
    } else if (i < s0 + s1) {
        int j = i - s0, n = j / 160, k = j - n * 160;
        Wt2a[j] = __float2bfloat16((n < HID_ && k < HID_) ? Wa2[k * HID_ + n] : 0.f);
    } else if (i < s0 + s1 + s2) {
        int j = i - s0 - s1, n = j / 3072, k = j - n * 3072;
        Wt1s[j] = __float2bfloat16(n < HID_ ? Ws1[k * HID_ + n] : 0.f);
    } else if (i < s0 + s1 + s2 + s3) {
        int j = i - s0 - s1 - s2, n = j / 160, k = j - n * 160;
        Wt2s[j] = __float2bfloat16((n < HID_ && k < HID_) ? Ws2[k * HID_ + n] : 0.f);
    }
}

// attn MLP: 1024 -> 150 relu -> 150 relu -> 1, 64 rows/block, 4 waves.
// A(f32)+B(bf16) DMA-staged per 64-K chunk, 2-phase dbuf (R8 structure).
template<int K1>
__global__ __launch_bounds__(256, 2)
void mlp_mfma(const float* __restrict__ xin,
              const __hip_bfloat16* __restrict__ Wt1, const float* __restrict__ b1,
              const __hip_bfloat16* __restrict__ Wt2, const float* __restrict__ b2,
              const float* __restrict__ W3, const float* __restrict__ b3,
              float* __restrict__ outp)
{
    constexpr int NC  = K1 / 64;
    constexpr int ACH = 64 * 64 * 4;
    constexpr int BCH = 160 * 64 * 2;
    __shared__ __align__(16) char smem[2 * ACH + 2 * BCH];

    const int tid  = threadIdx.x;
    const int lane = tid & 63;
    const int w    = tid >> 6;
    const int rg   = w >> 1;
    const int cg   = w & 1;
    const int lr   = lane & 15;
    const int hi   = lane >> 4;

    const long long row0 = (long long)blockIdx.x * MROWS;

    auto stageA = [&](int bi, int c) {
        char* dst = smem + bi * ACH;
#pragma unroll
        for (int j = 0; j < 4; ++j) {
            const int row  = (w * 4 + j) * 4 + (lane >> 4);
            const int slot = (lane & 15) ^ (row & 7);
            gload16(xin + (row0 + row) * (long long)K1 + c * 64 + slot * 4,
                    dst + (w * 4 + j) * 1024);
        }
    };
    auto stageB = [&](int bi, int c) {
        char* dst = smem + 2 * ACH + bi * BCH;
#pragma unroll
        for (int j = 0; j < 5; ++j) {
            const int nrow = (w * 5 + j) * 8 + (lane >> 3);
            const int slot = (lane & 7) ^ (nrow & 7);
            gload16(Wt1 + (long long)nrow * K1 + c * 64 + slot * 8,
                    dst + (w * 5 + j) * 1024);
        }
    };

    f32x4 acc[2][5];
#pragma unroll
    for (int rt = 0; rt < 2; ++rt)
#pragma unroll
        for (int nt = 0; nt < 5; ++nt) acc[rt][nt] = (f32x4){0.f, 0.f, 0.f, 0.f};

    stageA(0, 0);
    stageB(0, 0);

    for (int c = 0; c < NC; ++c) {
        __syncthreads();
        if (c + 1 < NC) { stageA((c + 1) & 1, c + 1); stageB((c + 1) & 1, c + 1); }
        const int bi = c & 1;
        const char* sA = smem + bi * ACH;
        const char* sB = smem + 2 * ACH + bi * BCH;
#pragma unroll
        for (int ks = 0; ks < 2; ++ks) {
            short8 bfr[5];
#pragma unroll
            for (int nt = 0; nt < 5; ++nt) {
                const int nrow = cg * 80 + nt * 16 + lr;
                const int slot = (ks * 4 + hi) ^ (nrow & 7);
                bfr[nt] = *(const short8*)(sB + nrow * 128 + slot * 16);
            }
#pragma unroll
            for (int rt = 0; rt < 2; ++rt) {
                const int r = rg * 32 + rt * 16 + lr;
                const int s0i = (ks * 8 + hi * 2) ^ (r & 7);
                const int s1i = (ks * 8 + hi * 2 + 1) ^ (r & 7);
                float4 a0 = *(const float4*)(sA + r * 256 + s0i * 16);
                float4 a1 = *(const float4*)(sA + r * 256 + s1i * 16);
                short8 afr = pack8(a0, a1);
#pragma unroll
                for (int nt = 0; nt < 5; ++nt)
                    acc[rt][nt] = __builtin_amdgcn_mfma_f32_16x16x32_bf16(
                        afr, bfr[nt], acc[rt][nt], 0, 0, 0);
            }
        }
    }
    __syncthreads();

    __hip_bfloat16* hl = (__hip_bfloat16*)smem;

#pragma unroll
    for (int nt = 0; nt < 5; ++nt) {
        const int ch = cg * 80 + nt * 16 + lr;
        const float bb = (ch < HID_) ? b1[ch] : 0.f;
#pragma unroll
        for (int rt = 0; rt < 2; ++rt)
#pragma unroll
            for (int r4 = 0; r4 < 4; ++r4) {
                const int row = rg * 32 + rt * 16 + hi * 4 + r4;
                float h = acc[rt][nt][r4] + bb;
                hl[row * LSTR + ch] = __float2bfloat16(h > 0.f ? h : 0.f);
            }
    }
    __syncthreads();

    f32x4 acc2[2][5];
#pragma unroll
    for (int rt = 0; rt < 2; ++rt)
#pragma unroll
        for (int nt = 0; nt < 5; ++nt) acc2[rt][nt] = (f32x4){0.f, 0.f, 0.f, 0.f};

#pragma unroll
    for (int ks = 0; ks < 5; ++ks) {
        const int k0 = ks * 32 + hi * 8;
        short8 bfr[5];
#pragma unroll
        for (int nt = 0; nt < 5; ++nt)
            bfr[nt] = *(const short8*)(Wt2 + (cg * 80 + nt * 16 + lr) * NPAD + k0);
#pragma unroll
        for (int rt = 0; rt < 2; ++rt) {
            short8 afr = *(const short8*)&hl[(rg * 32 + rt * 16 + lr) * LSTR + k0];
#pragma unroll
            for (int nt = 0; nt < 5; ++nt)
                acc2[rt][nt] = __builtin_amdgcn_mfma_f32_16x16x32_bf16(
                    afr, bfr[nt], acc2[rt][nt], 0, 0, 0);
        }
    }
    __syncthreads();

#pragma unroll
    for (int nt = 0; nt < 5; ++nt) {
        const int ch = cg * 80 + nt * 16 + lr;
        const float bb = (ch < HID_) ? b2[ch] : 0.f;
#pragma unroll
        for (int rt = 0; rt < 2; ++rt)
#pragma unroll
            for (int r4 = 0; r4 < 4; ++r4) {
                const int row = rg * 32 + rt * 16 + hi * 4 + r4;
                float h = acc2[rt][nt][r4] + bb;
                hl[row * LSTR + ch] = __float2bfloat16(h > 0.f ? h : 0.f);
            }
    }
    __syncthreads();

    {
        const int row = tid >> 2, quad = tid & 3;
        const int kb = quad * 38;
        const int ke = (kb + 38 > HID_) ? HID_ : kb + 38;
        float s = 0.f;
        for (int k = kb; k < ke; ++k)
            s += __bfloat162float(hl[row * LSTR + k]) * W3[k];
        s += __shfl_xor(s, 1);
        s += __shfl_xor(s, 2);
        if (quad == 0) outp[row0 + row] = s + b3[0];
    }
}

// Fused span construction + score MLP. 64 spans/block, 512 threads (8 waves).
// Sum chunks: branchless fixed-24-trip unrolled loop (weight zeroing) so the
// 48 float4 loads batch in flight instead of serializing (R10: VGPR=52 tell).
__global__ __launch_bounds__(512, 4)
void span_score(const float* __restrict__ x, const float* __restrict__ attn,
                const int* __restrict__ starts, const int* __restrict__ lengths,
                const int* __restrict__ nspans,
                const __hip_bfloat16* __restrict__ Wt1, const float* __restrict__ b1,
                const __hip_bfloat16* __restrict__ Wt2, const float* __restrict__ b2,
                const float* __restrict__ W3, const float* __restrict__ b3,
                float* __restrict__ spanout, float* __restrict__ scoreout)
{
    // layout: sA dbuf 2x8KB @0 ; sB dbuf 2x20KB @16384 ; meta @57344
    __shared__ __align__(16) char smem[58112];
    int* stL = (int*)(smem + 57344);
    int* enL = (int*)(smem + 57600);
    int* bL  = (int*)(smem + 57856);

    const int tid  = threadIdx.x;
    const int lane = tid & 63;
    const int w    = tid >> 6;     // 0..7
    const int rg   = w >> 1;       // 0..3 : rows rg*16..+16
    const int cg   = w & 1;        // cols cg*80..+80
    const int lr   = lane & 15;
    const int hi   = lane >> 4;

    // bijective XCD-aware swizzle over 500 blocks (q=62, r=4)
    int bid = blockIdx.x;
    {
        const int qq = 500 / 8, rr = 500 % 8;
        const int xcd = bid % 8, i = bid / 8;
        bid = (xcd < rr ? xcd * (qq + 1) : rr * (qq + 1) + (xcd - rr) * qq) + i;
    }
    const int span0 = bid * 64;

    if (tid < 64) {
        const int sp = span0 + tid;
        const int b  = sp / S_;
        const int s  = sp - b * S_;
        const bool val = s < nspans[b];
        const int st = val ? starts[sp] : 0;
        stL[tid] = st;
        enL[tid] = val ? (st + lengths[sp]) : -1;
        bL[tid]  = b;
    }
    __syncthreads();

    const int r    = tid >> 3;     // constructor row 0..63
    const int q    = tid & 7;      // 8 floats per thread
    const int st_r = stL[r];
    const int en_r = enL[r];       // -1 for invalid spans
    const long long sp_r = span0 + r;
    const float* xb = x + (long long)bL[r] * T_ * E_;
    const float* ab = attn + bL[r] * T_;

    auto constructA = [&](int bi, int c) {
        float4 v0, v1;
        if (c < 32) {
            if (en_r >= st_r) {
                const int srow = (c < 16) ? st_r : en_r;
                const float* p = xb + (long long)srow * E_ + (c & 15) * 64 + q * 8;
                v0 = *(const float4*)p;
                v1 = *(const float4*)(p + 4);
            } else {
                v0 = make_float4(0.f, 0.f, 0.f, 0.f);
                v1 = make_float4(0.f, 0.f, 0.f, 0.f);
            }
        } else {
            // branchless ragged sum: st <= T-33, len < 24 => st+23 < T (safe)
            const int cl = (c - 32) * 64 + q * 8;
            const float* p0 = xb + (long long)st_r * E_ + cl;
            float4 A0[4], A1[4];
#pragma unroll
            for (int g = 0; g < 4; ++g) {
                A0[g] = make_float4(0.f, 0.f, 0.f, 0.f);
                A1[g] = make_float4(0.f, 0.f, 0.f, 0.f);
            }
#pragma unroll
            for (int u = 0; u < 24; ++u) {
                const int t = st_r + u;
                const float wv = (t <= en_r) ? ab[t] : 0.f;
                const float4 u0 = *(const float4*)(p0 + u * E_);
                const float4 u1 = *(const float4*)(p0 + u * E_ + 4);
                const int g = u & 3;
                A0[g].x += u0.x * wv; A0[g].y += u0.y * wv;
                A0[g].z += u0.z * wv; A0[g].w += u0.w * wv;
                A1[g].x += u1.x * wv; A1[g].y += u1.y * wv;
                A1[g].z += u1.z * wv; A1[g].w += u1.w * wv;
            }
            v0 = make_float4(A0[0].x + A0[1].x + A0[2].x + A0[3].x,
                             A0[0].y + A0[1].y + A0[2].y + A0[3].y,
                             A0[0].z + A0[1].z + A0[2].z + A0[3].z,
                             A0[0].w + A0[1].w + A0[2].w + A0[3].w);
            v1 = make_float4(A1[0].x + A1[1].x + A1[2].x + A1[3].x,
                             A1[0].y + A1[1].y + A1[2].y + A1[3].y,
                             A1[0].z + A1[1].z + A1[2].z + A1[3].z,
                             A1[0].w + A1[1].w + A1[2].w + A1[3].w);
        }
        float* orow = spanout + sp_r * (3 * E_) + c * 64 + q * 8;
        *(float4*)orow       = v0;
        *(float4*)(orow + 4) = v1;
        *(short8*)(smem + bi * 8192 + r * 128 + ((q ^ (r & 7)) * 16)) = pack8(v0, v1);
    };

    auto stageB = [&](int bi, int c) {
        char* dst = smem + 16384 + bi * 20480;
#pragma unroll
        for (int j = 0; j < 3; ++j) {
            const int idx = w * 3 + j;      // 20 x 1KB pieces over 8 waves
            if (idx < 20) {
                const int nrow = idx * 8 + (lane >> 3);
                const int slot = (lane & 7) ^ (nrow & 7);
                gload16(Wt1 + (long long)nrow * GI_ + c * 64 + slot * 8,
                        dst + idx * 1024);
            }
        }
    };

    // ---------------- stage 1: 3072 -> 160 ----------------
    f32x4 acc[5];
#pragma unroll
    for (int nt = 0; nt < 5; ++nt) acc[nt] = (f32x4){0.f, 0.f, 0.f, 0.f};

    constructA(0, 0);
    stageB(0, 0);

    for (int c = 0; c < 48; ++c) {
        __syncthreads();                 // A[c],B[c] ready; buf^1 reads done
        if (c + 1 < 48) stageB((c + 1) & 1, c + 1);
        const int bi = c & 1;
        const char* sAc = smem + bi * 8192;
        const char* sBc = smem + 16384 + bi * 20480;
#pragma unroll
        for (int ks = 0; ks < 2; ++ks) {
            short8 bfr[5];
#pragma unroll
            for (int nt = 0; nt < 5; ++nt) {
                const int nrow = cg * 80 + nt * 16 + lr;
                const int slot = (ks * 4 + hi) ^ (nrow & 7);
                bfr[nt] = *(const short8*)(sBc + nrow * 128 + slot * 16);
            }
            const int r2 = rg * 16 + lr;
            const int sl = (ks * 4 + hi) ^ (r2 & 7);
            short8 afr = *(const short8*)(sAc + r2 * 128 + sl * 16);
#pragma unroll
            for (int nt = 0; nt < 5; ++nt)
                acc[nt] = __builtin_amdgcn_mfma_f32_16x16x32_bf16(
                    afr, bfr[nt], acc[nt], 0, 0, 0);
        }
        if (c + 1 < 48) constructA((c + 1) & 1, c + 1);
    }
    __syncthreads();   // stage-1 LDS reads done; smem reusable

    __hip_bfloat16* hl = (__hip_bfloat16*)smem;   // 21.5 KB alias

#pragma unroll
    for (int nt = 0; nt < 5; ++nt) {
        const int ch = cg * 80 + nt * 16 + lr;
        const float bb = (ch < HID_) ? b1[ch] : 0.f;
#pragma unroll
        for (int r4 = 0; r4 < 4; ++r4) {
            const int row = rg * 16 + hi * 4 + r4;
            float h = acc[nt][r4] + bb;
            hl[row * LSTR + ch] = __float2bfloat16(h > 0.f ? h : 0.f);
        }
    }
    __syncthreads();

    // ---------------- stage 2: 160 -> 160 ----------------
    f32x4 acc2[5];
#pragma unroll
    for (int nt = 0; nt < 5; ++nt) acc2[nt] = (f32x4){0.f, 0.f, 0.f, 0.f};

#pragma unroll
    for (int ks = 0; ks < 5; ++ks) {
        const int k0 = ks * 32 + hi * 8;
        short8 bfr[5];
#pragma unroll
        for (int nt = 0; nt < 5; ++nt)
            bfr[nt] = *(const short8*)(Wt2 + (cg * 80 + nt * 16 + lr) * NPAD + k0);
        short8 afr = *(const short8*)&hl[(rg * 16 + lr) * LSTR + k0];
#pragma unroll
        for (int nt = 0; nt < 5; ++nt)
            acc2[nt] = __builtin_amdgcn_mfma_f32_16x16x32_bf16(
                afr, bfr[nt], acc2[nt], 0, 0, 0);
    }
    __syncthreads();

#pragma unroll
    for (int nt = 0; nt < 5; ++nt) {
        const int ch = cg * 80 + nt * 16 + lr;
        const float bb = (ch < HID_) ? b2[ch] : 0.f;
#pragma unroll
        for (int r4 = 0; r4 < 4; ++r4) {
            const int row = rg * 16 + hi * 4 + r4;
            float h = acc2[nt][r4] + bb;
            hl[row * LSTR + ch] = __float2bfloat16(h > 0.f ? h : 0.f);
        }
    }
    __syncthreads();

    // ---------------- stage 3: 150 -> 1 (8 threads/row) ----------------
    {
        const int row = tid >> 3, oct = tid & 7;
        const int kb = oct * 19;
        const int ke = (kb + 19 > HID_) ? HID_ : kb + 19;
        float s = 0.f;
        for (int k = kb; k < ke; ++k)
            s += __bfloat162float(hl[row * LSTR + k]) * W3[k];
        s += __shfl_xor(s, 1);
        s += __shfl_xor(s, 2);
        s += __shfl_xor(s, 4);
        if (oct == 0) scoreout[span0 + row] = s + b3[0];
    }
}

extern "C" void kernel_launch(void* const* d_in, const int* in_sizes, int n_in,
                              void* d_out, int out_size, void* d_ws, size_t ws_size,
                              hipStream_t stream) {
    const float* x       = (const float*)d_in[0];
    const int*   starts  = (const int*)d_in[1];
    const int*   lengths = (const int*)d_in[2];
    const int*   nspans  = (const int*)d_in[3];
    const float* Wa1 = (const float*)d_in[4];
    const float* ba1 = (const float*)d_in[5];
    const float* Wa2 = (const float*)d_in[6];
    const float* ba2 = (const float*)d_in[7];
    const float* Wa3 = (const float*)d_in[8];
    const float* ba3 = (const float*)d_in[9];
    const float* Ws1 = (const float*)d_in[10];
    const float* bs1 = (const float*)d_in[11];
    const float* Ws2 = (const float*)d_in[12];
    const float* bs2 = (const float*)d_in[13];
    const float* Ws3 = (const float*)d_in[14];
    const float* bs3 = (const float*)d_in[15];

    float* out        = (float*)d_out;                       // span_emb [B,S,3E]
    float* out_scores = out + (long long)B_ * S_ * 3 * E_;   // scores [B,S]

    char* ws = (char*)d_ws;
    float*          attn = (float*)ws;                       // 131072 B
    __hip_bfloat16* Wt1a = (__hip_bfloat16*)(ws + 131072);   // 160*1024*2
    __hip_bfloat16* Wt2a = (__hip_bfloat16*)(ws + 458752);   // 160*160*2
    __hip_bfloat16* Wt1s = (__hip_bfloat16*)(ws + 509952);   // 160*3072*2
    __hip_bfloat16* Wt2s = (__hip_bfloat16*)(ws + 1492992);  // 160*160*2

    // 0) weight transposes
    transpose_all<<<2760, 256, 0, stream>>>(Wa1, Wa2, Ws1, Ws2,
                                            Wt1a, Wt2a, Wt1s, Wt2s);

    // 1) attention score per token (32768 rows, 512 blocks)
    mlp_mfma<E_><<<(B_ * T_) / MROWS, 256, 0, stream>>>
        (x, Wt1a, ba1, Wt2a, ba2, Wa3, ba3, attn);

    // 2) fused span construction + mention-score MLP (500 blocks)
    span_score<<<500, 512, 0, stream>>>
        (x, attn, starts, lengths, nspans,
         Wt1s, bs1, Wt2s, bs2, Ws3, bs3, out, out_scores);
}

// Round 12
// 271.647 us; speedup vs baseline: 5.5098x; 5.5098x over previous
//
#include <hip/hip_runtime.h>
#include <hip/hip_bf16.h>

#define B_   16
#define T_   2048
#define E_   1024
#define S_   2000
#define HID_ 150
#define GI_  3072

typedef __attribute__((ext_vector_type(8))) short short8;   // 8 bf16 (4 VGPRs)
typedef __attribute__((ext_vector_type(4))) float f32x4;

constexpr int NPAD  = 160;   // HID padded to 10 MFMA col-tiles
constexpr int LSTR  = 168;   // hl row stride (bf16): 336 B
constexpr int MROWS = 64;    // rows per MLP block

__device__ __forceinline__ void gload16(const void* gsrc, void* ldst) {
    __builtin_amdgcn_global_load_lds(
        (const __attribute__((address_space(1))) unsigned int*)gsrc,
        (__attribute__((address_space(3))) unsigned int*)ldst,
        16, 0, 0);   // 16B/lane, wave-uniform LDS base + lane*16
}

__device__ __forceinline__ short8 pack8(float4 a, float4 b) {
    union { __hip_bfloat162 h[4]; short8 s; } u;
    u.h[0] = __float22bfloat162_rn(make_float2(a.x, a.y));
    u.h[1] = __float22bfloat162_rn(make_float2(a.z, a.w));
    u.h[2] = __float22bfloat162_rn(make_float2(b.x, b.y));
    u.h[3] = __float22bfloat162_rn(make_float2(b.z, b.w));
    return u.s;
}

__device__ __forceinline__ short8 pack8v(f32x4 a, f32x4 b) {
    union { __hip_bfloat162 h[4]; short8 s; } u;
    u.h[0] = __float22bfloat162_rn(make_float2(a.x, a.y));
    u.h[1] = __float22bfloat162_rn(make_float2(a.z, a.w));
    u.h[2] = __float22bfloat162_rn(make_float2(b.x, b.y));
    u.h[3] = __float22bfloat162_rn(make_float2(b.z, b.w));
    return u.s;
}

// All four weight transposes (f32 [K][150] -> bf16 [160][K], zero-padded).
__global__ __launch_bounds__(256)
void transpose_all(const float* __restrict__ Wa1, const float* __restrict__ Wa2,
                   const float* __restrict__ Ws1, const float* __restrict__ Ws2,
                   __hip_bfloat16* __restrict__ Wt1a, __hip_bfloat16* __restrict__ Wt2a,
                   __hip_bfloat16* __restrict__ Wt1s, __hip_bfloat16* __restrict__ Wt2s)
{
    const int s0 = 160 * 1024, s1 = 160 * 160, s2 = 160 * 3072, s3 = 160 * 160;
    int i = blockIdx.x * 256 + threadIdx.x;
    if (i < s0) {
        int n = i >> 10, k = i & 1023;
        Wt1a[i] = __float2bfloat16(n < HID_ ? Wa1[k * HID_ + n] : 0.f);
    } else if (i < s0 + s1) {
        int j = i - s0, n = j / 160, k = j - n * 160;
        Wt2a[j] = __float2bfloat16((n < HID_ && k < HID_) ? Wa2[k * HID_ + n] : 0.f);
    } else if (i < s0 + s1 + s2) {
        int j = i - s0 - s1, n = j / 3072, k = j - n * 3072;
        Wt1s[j] = __float2bfloat16(n < HID_ ? Ws1[k * HID_ + n] : 0.f);
    } else if (i < s0 + s1 + s2 + s3) {
        int j = i - s0 - s1 - s2, n = j / 160, k = j - n * 160;
        Wt2s[j] = __float2bfloat16((n < HID_ && k < HID_) ? Ws2[k * HID_ + n] : 0.f);
    }
}

// attn MLP: 1024 -> 150 relu -> 150 relu -> 1, 64 rows/block, 4 waves.
// A(f32)+B(bf16) DMA-staged per 64-K chunk, 2-phase dbuf (R8 structure).
template<int K1>
__global__ __launch_bounds__(256, 2)
void mlp_mfma(const float* __restrict__ xin,
              const __hip_bfloat16* __restrict__ Wt1, const float* __restrict__ b1,
              const __hip_bfloat16* __restrict__ Wt2, const float* __restrict__ b2,
              const float* __restrict__ W3, const float* __restrict__ b3,
              float* __restrict__ outp)
{
    constexpr int NC  = K1 / 64;
    constexpr int ACH = 64 * 64 * 4;
    constexpr int BCH = 160 * 64 * 2;
    __shared__ __align__(16) char smem[2 * ACH + 2 * BCH];

    const int tid  = threadIdx.x;
    const int lane = tid & 63;
    const int w    = tid >> 6;
    const int rg   = w >> 1;
    const int cg   = w & 1;
    const int lr   = lane & 15;
    const int hi   = lane >> 4;

    const long long row0 = (long long)blockIdx.x * MROWS;

    auto stageA = [&](int bi, int c) {
        char* dst = smem + bi * ACH;
#pragma unroll
        for (int j = 0; j < 4; ++j) {
            const int row  = (w * 4 + j) * 4 + (lane >> 4);
            const int slot = (lane & 15) ^ (row & 7);
            gload16(xin + (row0 + row) * (long long)K1 + c * 64 + slot * 4,
                    dst + (w * 4 + j) * 1024);
        }
    };
    auto stageB = [&](int bi, int c) {
        char* dst = smem + 2 * ACH + bi * BCH;
#pragma unroll
        for (int j = 0; j < 5; ++j) {
            const int nrow = (w * 5 + j) * 8 + (lane >> 3);
            const int slot = (lane & 7) ^ (nrow & 7);
            gload16(Wt1 + (long long)nrow * K1 + c * 64 + slot * 8,
                    dst + (w * 5 + j) * 1024);
        }
    };

    f32x4 acc[2][5];
#pragma unroll
    for (int rt = 0; rt < 2; ++rt)
#pragma unroll
        for (int nt = 0; nt < 5; ++nt) acc[rt][nt] = (f32x4){0.f, 0.f, 0.f, 0.f};

    stageA(0, 0);
    stageB(0, 0);

    for (int c = 0; c < NC; ++c) {
        __syncthreads();
        if (c + 1 < NC) { stageA((c + 1) & 1, c + 1); stageB((c + 1) & 1, c + 1); }
        const int bi = c & 1;
        const char* sA = smem + bi * ACH;
        const char* sB = smem + 2 * ACH + bi * BCH;
#pragma unroll
        for (int ks = 0; ks < 2; ++ks) {
            short8 bfr[5];
#pragma unroll
            for (int nt = 0; nt < 5; ++nt) {
                const int nrow = cg * 80 + nt * 16 + lr;
                const int slot = (ks * 4 + hi) ^ (nrow & 7);
                bfr[nt] = *(const short8*)(sB + nrow * 128 + slot * 16);
            }
#pragma unroll
            for (int rt = 0; rt < 2; ++rt) {
                const int r = rg * 32 + rt * 16 + lr;
                const int s0i = (ks * 8 + hi * 2) ^ (r & 7);
                const int s1i = (ks * 8 + hi * 2 + 1) ^ (r & 7);
                float4 a0 = *(const float4*)(sA + r * 256 + s0i * 16);
                float4 a1 = *(const float4*)(sA + r * 256 + s1i * 16);
                short8 afr = pack8(a0, a1);
#pragma unroll
                for (int nt = 0; nt < 5; ++nt)
                    acc[rt][nt] = __builtin_amdgcn_mfma_f32_16x16x32_bf16(
                        afr, bfr[nt], acc[rt][nt], 0, 0, 0);
            }
        }
    }
    __syncthreads();

    __hip_bfloat16* hl = (__hip_bfloat16*)smem;

#pragma unroll
    for (int nt = 0; nt < 5; ++nt) {
        const int ch = cg * 80 + nt * 16 + lr;
        const float bb = (ch < HID_) ? b1[ch] : 0.f;
#pragma unroll
        for (int rt = 0; rt < 2; ++rt)
#pragma unroll
            for (int r4 = 0; r4 < 4; ++r4) {
                const int row = rg * 32 + rt * 16 + hi * 4 + r4;
                float h = acc[rt][nt][r4] + bb;
                hl[row * LSTR + ch] = __float2bfloat16(h > 0.f ? h : 0.f);
            }
    }
    __syncthreads();

    f32x4 acc2[2][5];
#pragma unroll
    for (int rt = 0; rt < 2; ++rt)
#pragma unroll
        for (int nt = 0; nt < 5; ++nt) acc2[rt][nt] = (f32x4){0.f, 0.f, 0.f, 0.f};

#pragma unroll
    for (int ks = 0; ks < 5; ++ks) {
        const int k0 = ks * 32 + hi * 8;
        short8 bfr[5];
#pragma unroll
        for (int nt = 0; nt < 5; ++nt)
            bfr[nt] = *(const short8*)(Wt2 + (cg * 80 + nt * 16 + lr) * NPAD + k0);
#pragma unroll
        for (int rt = 0; rt < 2; ++rt) {
            short8 afr = *(const short8*)&hl[(rg * 32 + rt * 16 + lr) * LSTR + k0];
#pragma unroll
            for (int nt = 0; nt < 5; ++nt)
                acc2[rt][nt] = __builtin_amdgcn_mfma_f32_16x16x32_bf16(
                    afr, bfr[nt], acc2[rt][nt], 0, 0, 0);
        }
    }
    __syncthreads();

#pragma unroll
    for (int nt = 0; nt < 5; ++nt) {
        const int ch = cg * 80 + nt * 16 + lr;
        const float bb = (ch < HID_) ? b2[ch] : 0.f;
#pragma unroll
        for (int rt = 0; rt < 2; ++rt)
#pragma unroll
            for (int r4 = 0; r4 < 4; ++r4) {
                const int row = rg * 32 + rt * 16 + hi * 4 + r4;
                float h = acc2[rt][nt][r4] + bb;
                hl[row * LSTR + ch] = __float2bfloat16(h > 0.f ? h : 0.f);
            }
    }
    __syncthreads();

    {
        const int row = tid >> 2, quad = tid & 3;
        const int kb = quad * 38;
        const int ke = (kb + 38 > HID_) ? HID_ : kb + 38;
        float s = 0.f;
        for (int k = kb; k < ke; ++k)
            s += __bfloat162float(hl[row * LSTR + k]) * W3[k];
        s += __shfl_xor(s, 1);
        s += __shfl_xor(s, 2);
        if (quad == 0) outp[row0 + row] = s + b3[0];
    }
}

// Fused span construction + score MLP. 64 spans/block, 512 threads (8 waves).
// Sum: fixed-24-trip body (weight zeroing) with #pragma unroll 4 -> bounded
// load clustering (R11 full-unroll spilled: WRITE 3.2GB scratch tell).
__global__ __launch_bounds__(512, 4)
void span_score(const float* __restrict__ x, const float* __restrict__ attn,
                const int* __restrict__ starts, const int* __restrict__ lengths,
                const int* __restrict__ nspans,
                const __hip_bfloat16* __restrict__ Wt1, const float* __restrict__ b1,
                const __hip_bfloat16* __restrict__ Wt2, const float* __restrict__ b2,
                const float* __restrict__ W3, const float* __restrict__ b3,
                float* __restrict__ spanout, float* __restrict__ scoreout)
{
    // layout: sA dbuf 2x8KB @0 ; sB dbuf 2x20KB @16384 ; meta @57344
    __shared__ __align__(16) char smem[58112];
    int* stL = (int*)(smem + 57344);
    int* enL = (int*)(smem + 57600);
    int* bL  = (int*)(smem + 57856);

    const int tid  = threadIdx.x;
    const int lane = tid & 63;
    const int w    = tid >> 6;     // 0..7
    const int rg   = w >> 1;       // 0..3 : rows rg*16..+16
    const int cg   = w & 1;        // cols cg*80..+80
    const int lr   = lane & 15;
    const int hi   = lane >> 4;

    // bijective XCD-aware swizzle over 500 blocks (q=62, r=4)
    int bid = blockIdx.x;
    {
        const int qq = 500 / 8, rr = 500 % 8;
        const int xcd = bid % 8, i = bid / 8;
        bid = (xcd < rr ? xcd * (qq + 1) : rr * (qq + 1) + (xcd - rr) * qq) + i;
    }
    const int span0 = bid * 64;

    if (tid < 64) {
        const int sp = span0 + tid;
        const int b  = sp / S_;
        const int s  = sp - b * S_;
        const bool val = s < nspans[b];
        const int st = val ? starts[sp] : 0;
        stL[tid] = st;
        enL[tid] = val ? (st + lengths[sp]) : -1;
        bL[tid]  = b;
    }
    __syncthreads();

    const int r    = tid >> 3;     // constructor row 0..63
    const int q    = tid & 7;      // 8 floats per thread
    const int st_r = stL[r];
    const int en_r = enL[r];       // -1 for invalid spans
    const long long sp_r = span0 + r;
    const float* xb = x + (long long)bL[r] * T_ * E_;
    const float* ab = attn + bL[r] * T_;

    auto constructA = [&](int bi, int c) {
        f32x4 v0 = (f32x4){0.f, 0.f, 0.f, 0.f};
        f32x4 v1 = (f32x4){0.f, 0.f, 0.f, 0.f};
        if (c < 32) {
            if (en_r >= st_r) {
                const int srow = (c < 16) ? st_r : en_r;
                const float* p = xb + (long long)srow * E_ + (c & 15) * 64 + q * 8;
                v0 = *(const f32x4*)p;
                v1 = *(const f32x4*)(p + 4);
            }
        } else if (en_r >= st_r) {
            // branchless fixed-trip sum: st <= T-33, len < 24 => st+23 < T
            const int cl = (c - 32) * 64 + q * 8;
            const float* p0 = xb + (long long)st_r * E_ + cl;
            f32x4 a0 = v0, a1 = v0, b0 = v0, b1 = v0;
#pragma unroll 4
            for (int u = 0; u < 24; ++u) {
                const float wv = (st_r + u <= en_r) ? ab[st_r + u] : 0.f;
                const f32x4 u0 = *(const f32x4*)(p0 + u * E_);
                const f32x4 u1 = *(const f32x4*)(p0 + u * E_ + 4);
                if (u & 1) { b0 += u0 * wv; b1 += u1 * wv; }
                else       { a0 += u0 * wv; a1 += u1 * wv; }
            }
            v0 = a0 + b0;
            v1 = a1 + b1;
        }
        float* orow = spanout + sp_r * (3 * E_) + c * 64 + q * 8;
        *(f32x4*)orow       = v0;
        *(f32x4*)(orow + 4) = v1;
        *(short8*)(smem + bi * 8192 + r * 128 + ((q ^ (r & 7)) * 16)) = pack8v(v0, v1);
    };

    auto stageB = [&](int bi, int c) {
        char* dst = smem + 16384 + bi * 20480;
#pragma unroll
        for (int j = 0; j < 3; ++j) {
            const int idx = w * 3 + j;      // 20 x 1KB pieces over 8 waves
            if (idx < 20) {
                const int nrow = idx * 8 + (lane >> 3);
                const int slot = (lane & 7) ^ (nrow & 7);
                gload16(Wt1 + (long long)nrow * GI_ + c * 64 + slot * 8,
                        dst + idx * 1024);
            }
        }
    };

    // ---------------- stage 1: 3072 -> 160 ----------------
    f32x4 acc[5];
#pragma unroll
    for (int nt = 0; nt < 5; ++nt) acc[nt] = (f32x4){0.f, 0.f, 0.f, 0.f};

    constructA(0, 0);
    stageB(0, 0);

    for (int c = 0; c < 48; ++c) {
        __syncthreads();                 // A[c],B[c] ready; buf^1 reads done
        if (c + 1 < 48) stageB((c + 1) & 1, c + 1);
        const int bi = c & 1;
        const char* sAc = smem + bi * 8192;
        const char* sBc = smem + 16384 + bi * 20480;
#pragma unroll
        for (int ks = 0; ks < 2; ++ks) {
            short8 bfr[5];
#pragma unroll
            for (int nt = 0; nt < 5; ++nt) {
                const int nrow = cg * 80 + nt * 16 + lr;
                const int slot = (ks * 4 + hi) ^ (nrow & 7);
                bfr[nt] = *(const short8*)(sBc + nrow * 128 + slot * 16);
            }
            const int r2 = rg * 16 + lr;
            const int sl = (ks * 4 + hi) ^ (r2 & 7);
            short8 afr = *(const short8*)(sAc + r2 * 128 + sl * 16);
#pragma unroll
            for (int nt = 0; nt < 5; ++nt)
                acc[nt] = __builtin_amdgcn_mfma_f32_16x16x32_bf16(
                    afr, bfr[nt], acc[nt], 0, 0, 0);
        }
        if (c + 1 < 48) constructA((c + 1) & 1, c + 1);
    }
    __syncthreads();   // stage-1 LDS reads done; smem reusable

    __hip_bfloat16* hl = (__hip_bfloat16*)smem;   // 21.5 KB alias

#pragma unroll
    for (int nt = 0; nt < 5; ++nt) {
        const int ch = cg * 80 + nt * 16 + lr;
        const float bb = (ch < HID_) ? b1[ch] : 0.f;
#pragma unroll
        for (int r4 = 0; r4 < 4; ++r4) {
            const int row = rg * 16 + hi * 4 + r4;
            float h = acc[nt][r4] + bb;
            hl[row * LSTR + ch] = __float2bfloat16(h > 0.f ? h : 0.f);
        }
    }
    __syncthreads();

    // ---------------- stage 2: 160 -> 160 ----------------
    f32x4 acc2[5];
#pragma unroll
    for (int nt = 0; nt < 5; ++nt) acc2[nt] = (f32x4){0.f, 0.f, 0.f, 0.f};

#pragma unroll
    for (int ks = 0; ks < 5; ++ks) {
        const int k0 = ks * 32 + hi * 8;
        short8 bfr[5];
#pragma unroll
        for (int nt = 0; nt < 5; ++nt)
            bfr[nt] = *(const short8*)(Wt2 + (cg * 80 + nt * 16 + lr) * NPAD + k0);
        short8 afr = *(const short8*)&hl[(rg * 16 + lr) * LSTR + k0];
#pragma unroll
        for (int nt = 0; nt < 5; ++nt)
            acc2[nt] = __builtin_amdgcn_mfma_f32_16x16x32_bf16(
                afr, bfr[nt], acc2[nt], 0, 0, 0);
    }
    __syncthreads();

#pragma unroll
    for (int nt = 0; nt < 5; ++nt) {
        const int ch = cg * 80 + nt * 16 + lr;
        const float bb = (ch < HID_) ? b2[ch] : 0.f;
#pragma unroll
        for (int r4 = 0; r4 < 4; ++r4) {
            const int row = rg * 16 + hi * 4 + r4;
            float h = acc2[nt][r4] + bb;
            hl[row * LSTR + ch] = __float2bfloat16(h > 0.f ? h : 0.f);
        }
    }
    __syncthreads();

    // ---------------- stage 3: 150 -> 1 (8 threads/row) ----------------
    {
        const int row = tid >> 3, oct = tid & 7;
        const int kb = oct * 19;
        const int ke = (kb + 19 > HID_) ? HID_ : kb + 19;
        float s = 0.f;
        for (int k = kb; k < ke; ++k)
            s += __bfloat162float(hl[row * LSTR + k]) * W3[k];
        s += __shfl_xor(s, 1);
        s += __shfl_xor(s, 2);
        s += __shfl_xor(s, 4);
        if (oct == 0) scoreout[span0 + row] = s + b3[0];
    }
}

extern "C" void kernel_launch(void* const* d_in, const int* in_sizes, int n_in,
                              void* d_out, int out_size, void* d_ws, size_t ws_size,
                              hipStream_t stream) {
    const float* x       = (const float*)d_in[0];
    const int*   starts  = (const int*)d_in[1];
    const int*   lengths = (const int*)d_in[2];
    const int*   nspans  = (const int*)d_in[3];
    const float* Wa1 = (const float*)d_in[4];
    const float* ba1 = (const float*)d_in[5];
    const float* Wa2 = (const float*)d_in[6];
    const float* ba2 = (const float*)d_in[7];
    const float* Wa3 = (const float*)d_in[8];
    const float* ba3 = (const float*)d_in[9];
    const float* Ws1 = (const float*)d_in[10];
    const float* bs1 = (const float*)d_in[11];
    const float* Ws2 = (const float*)d_in[12];
    const float* bs2 = (const float*)d_in[13];
    const float* Ws3 = (const float*)d_in[14];
    const float* bs3 = (const float*)d_in[15];

    float* out        = (float*)d_out;                       // span_emb [B,S,3E]
    float* out_scores = out + (long long)B_ * S_ * 3 * E_;   // scores [B,S]

    char* ws = (char*)d_ws;
    float*          attn = (float*)ws;                       // 131072 B
    __hip_bfloat16* Wt1a = (__hip_bfloat16*)(ws + 131072);   // 160*1024*2
    __hip_bfloat16* Wt2a = (__hip_bfloat16*)(ws + 458752);   // 160*160*2
    __hip_bfloat16* Wt1s = (__hip_bfloat16*)(ws + 509952);   // 160*3072*2
    __hip_bfloat16* Wt2s = (__hip_bfloat16*)(ws + 1492992);  // 160*160*2

    // 0) weight transposes
    transpose_all<<<2760, 256, 0, stream>>>(Wa1, Wa2, Ws1, Ws2,
                                            Wt1a, Wt2a, Wt1s, Wt2s);

    // 1) attention score per token (32768 rows, 512 blocks)
    mlp_mfma<E_><<<(B_ * T_) / MROWS, 256, 0, stream>>>
        (x, Wt1a, ba1, Wt2a, ba2, Wa3, ba3, attn);

    // 2) fused span construction + mention-score MLP (500 blocks)
    span_score<<<500, 512, 0, stream>>>
        (x, attn, starts, lengths, nspans,
         Wt1s, bs1, Wt2s, bs2, Ws3, bs3, out, out_scores);
}